// Round 28
// baseline (85.636 us; speedup 1.0000x reference)
//
#include <hip/hip_runtime.h>
#include <math.h>

#define NJ 16
#define NV 778
#define M3 2334   // NV*3
#define NTB 168   // B n-tiles: 7 col-blocks x 24 subtiles (cols padded)

typedef float f32x4  __attribute__((ext_vector_type(4)));
typedef short bf16x8 __attribute__((ext_vector_type(8)));

__device__ __forceinline__ unsigned short f2bf(float x) {
    unsigned int u = __float_as_uint(x);
    unsigned int r = (u + 0x7FFF + ((u >> 16) & 1)) >> 16;   // RNE
    return (unsigned short)r;
}

__device__ __forceinline__ void rodrigues9(
    float t0, float t1, float t2,
    float& r0, float& r1, float& r2, float& r3, float& r4,
    float& r5, float& r6, float& r7, float& r8)
{
    const float eps = 1e-8f;
    float a0 = t0 + eps, a1 = t1 + eps, a2 = t2 + eps;
    float angle = sqrtf(a0*a0 + a1*a1 + a2*a2);
    float inv  = 1.0f / angle;
    float half = 0.5f * angle;
    float sh = sinf(half), chh = cosf(half);
    float qw = chh;
    float qx = sh * t0 * inv;
    float qy = sh * t1 * inv;
    float qz = sh * t2 * inv;
    float qn = 1.0f / sqrtf(qw*qw + qx*qx + qy*qy + qz*qz);
    qw *= qn; qx *= qn; qy *= qn; qz *= qn;
    float w2=qw*qw, x2=qx*qx, y2=qy*qy, z2=qz*qz;
    float wx=qw*qx, wy=qw*qy, wz=qw*qz;
    float xy=qx*qy, xz=qx*qz, yz=qy*qz;
    r0 = w2 + x2 - y2 - z2;
    r1 = 2.f*(xy - wz);
    r2 = 2.f*(wy + xz);
    r3 = 2.f*(wz + xy);
    r4 = w2 - x2 + y2 - z2;
    r5 = 2.f*(yz - wx);
    r6 = 2.f*(xz - wy);
    r7 = 2.f*(wx + yz);
    r8 = w2 - x2 - y2 + z2;
}

// d_out layout (floats): verts [N*2334] | joints [N*48] | Rs [N*144]
// d_ws layout (floats):  A [N*192] | Afrag | Bfrag | SJJT(528)
// Pipeline (3 launches):
//   k01{SJJT->ws + Rodrigues->Rs + B-frags + A-frags(inline Rodrigues)}
//   -> k2c{kinematic chain -> Aws; zero joints}
//   -> k34{MFMA GEMM (384-col tile) + blend (scalar-A, amortized 2x) +
//          partial joints -> atomicAdd}
//
// LAUNCH-BOUNDS LESSON (R4,R8): second arg w caps VGPR at 256/w -> only (B,1).
// LATENCY LESSONS (R9-R27): (a) multi-barrier per-sample blocks serialize;
// (b) wave-uniform bulk data -> SCALAR pipe from a PRIOR kernel (R23, R27:
// vector-A regressed -- vector pipe contention); (c) matmul K>=16 -> MFMA;
// (d) dependent launches ~3us; (e) fuse producer->consumer through LDS;
// (f) amortize per-block uniform loads over wider tiles (384 cols: A s_loads
// serve 128 verts).

// ---------------- K01: SJ/JT reductions + Rodrigues + B-frags + A-frags.
__global__ __launch_bounds__(256, 1) void k01_prep(
    const float* __restrict__ shapedirs,
    const float* __restrict__ posedirs,
    const float* __restrict__ Jreg,
    const float* __restrict__ vtemp,
    const float* __restrict__ theta,
    const float* __restrict__ beta,
    float* __restrict__ SJJT,     // ws, 528 floats
    float* __restrict__ RsOut,
    bf16x8* __restrict__ Bf,
    bf16x8* __restrict__ Af,
    int N)
{
    const int tid = threadIdx.x;
    const int rodBlocks = (N * NJ) / 256;        // 256
    const int nB = NTB * 5 * 64;                 // 53760
    const int bfBlocks = nB / 256;               // 210
    if (blockIdx.x < 44) {
        int task = blockIdx.x * 4 + (tid >> 6);   // 0..175
        int lane = tid & 63;
        if (task < 176) {
            int b = task >> 4;      // 0..10
            int j = task & 15;
            const float* src = (b < 10) ? (shapedirs + (size_t)b * M3) : vtemp;
            float a0 = 0.f, a1 = 0.f, a2 = 0.f;
            for (int v = lane; v < NV; v += 64) {
                float jr = Jreg[v * 16 + j];
                a0 = fmaf(src[v*3 + 0], jr, a0);
                a1 = fmaf(src[v*3 + 1], jr, a1);
                a2 = fmaf(src[v*3 + 2], jr, a2);
            }
#pragma unroll
            for (int m = 1; m < 64; m <<= 1) {
                a0 += __shfl_xor(a0, m);
                a1 += __shfl_xor(a1, m);
                a2 += __shfl_xor(a2, m);
            }
            if (lane == 0) {
                int base = (b < 10) ? (b*48 + j*3) : (480 + j*3);
                SJJT[base + 0] = a0;
                SJJT[base + 1] = a1;
                SJJT[base + 2] = a2;
            }
        }
        return;
    }
    if (blockIdx.x < 44 + rodBlocks) {
        int idx = (blockIdx.x - 44) * 256 + tid;
        int n = idx >> 4;
        int j = idx & 15;
        float r0,r1,r2,r3,r4,r5,r6,r7,r8;
        rodrigues9(theta[n*48 + j*3 + 0], theta[n*48 + j*3 + 1],
                   theta[n*48 + j*3 + 2], r0,r1,r2,r3,r4,r5,r6,r7,r8);
        float* R = RsOut + (size_t)idx * 9;
        R[0]=r0; R[1]=r1; R[2]=r2; R[3]=r3; R[4]=r4;
        R[5]=r5; R[6]=r6; R[7]=r7; R[8]=r8;
        return;
    }
    if (blockIdx.x < 44 + rodBlocks + bfBlocks) {
        int idx = (blockIdx.x - 44 - rodBlocks) * 256 + tid;
        int lane = idx & 63;
        int ks   = (idx >> 6) % 5;
        int nt   = idx / 320;
        int col = nt * 16 + (lane & 15);
        int k0  = ks * 32 + (lane >> 4) * 8;
        bf16x8 o;
#pragma unroll
        for (int j = 0; j < 8; ++j) {
            int k = k0 + j;
            float val = 0.f;
            if (col < M3) {
                if (k < 10)       val = shapedirs[(size_t)k * M3 + col];
                else if (k < 145) val = posedirs[(size_t)(k - 10) * M3 + col];
            }
            o[j] = (short)f2bf(val);
        }
        Bf[idx] = o;
        return;
    }
    // A-frag packing with INLINE Rodrigues (validated R23/R24)
    int idx = (blockIdx.x - 44 - rodBlocks - bfBlocks) * 256 + tid;
    int nA = (N / 16) * 5 * 64;
    if (idx >= nA) return;
    int lane = idx & 63;
    int ks   = (idx >> 6) % 5;
    int mt   = idx / 320;
    int n  = mt * 16 + (lane & 15);
    int k0 = ks * 32 + (lane >> 4) * 8;

    int kkA = k0 - 10;
    int jA  = (kkA < 0) ? 0 : (kkA > 134 ? 14 : kkA / 9);
    int kkB = k0 - 3;
    int jB  = (kkB < 0) ? 0 : (kkB > 134 ? 14 : kkB / 9);

    float ra0,ra1,ra2,ra3,ra4,ra5,ra6,ra7,ra8;
    rodrigues9(theta[n*48 + (jA+1)*3 + 0], theta[n*48 + (jA+1)*3 + 1],
               theta[n*48 + (jA+1)*3 + 2], ra0,ra1,ra2,ra3,ra4,ra5,ra6,ra7,ra8);
    float rb0,rb1,rb2,rb3,rb4,rb5,rb6,rb7,rb8;
    rodrigues9(theta[n*48 + (jB+1)*3 + 0], theta[n*48 + (jB+1)*3 + 1],
               theta[n*48 + (jB+1)*3 + 2], rb0,rb1,rb2,rb3,rb4,rb5,rb6,rb7,rb8);

    bf16x8 o;
#pragma unroll
    for (int j = 0; j < 8; ++j) {
        int k = k0 + j;
        float val;
        if (k < 10) {
            val = beta[(size_t)n * 10 + k];
        } else if (k < 145) {
            int kk = k - 10;
            int jj = kk / 9;
            int rr = kk - jj * 9;
            float sa = (rr==0)?ra0:(rr==1)?ra1:(rr==2)?ra2:(rr==3)?ra3:
                       (rr==4)?ra4:(rr==5)?ra5:(rr==6)?ra6:(rr==7)?ra7:ra8;
            float sb = (rr==0)?rb0:(rr==1)?rb1:(rr==2)?rb2:(rr==3)?rb3:
                       (rr==4)?rb4:(rr==5)?rb5:(rr==6)?rb6:(rr==7)?rb7:rb8;
            float vv = (jj == jA) ? sa : sb;
            if ((rr & 3) == 0) vv -= 1.f;
            val = vv;
        } else {
            val = 0.f;
        }
        o[j] = (short)f2bf(val);
    }
    Af[idx] = o;
}

// ---------------- K2C: kinematic chain -> Aws; zero joints for k34 atomics.
__global__ __launch_bounds__(256, 1) void k2c_chain(
    const float* __restrict__ beta,
    const float* __restrict__ Rs,
    const float* __restrict__ SJJT,   // ws
    float* __restrict__ Aws,
    float* __restrict__ joints,       // zeroed here
    int N)
{
    const int tid = threadIdx.x;
    const int KB = (N * 5 + 255) / 256;          // 80
    if (blockIdx.x >= KB) {
        int idx = (blockIdx.x - KB) * 256 + tid;
        if (idx < N * 48) joints[idx] = 0.f;
        return;
    }
    __shared__ float sS[528];
    for (int i = tid; i < 528; i += 256) sS[i] = SJJT[i];
    __syncthreads();
    int gid = blockIdx.x * 256 + tid;
    if (gid >= N * 5) return;
    int n  = gid / 5;
    int ch = gid % 5;

    float b[10];
#pragma unroll
    for (int i = 0; i < 10; ++i) b[i] = beta[n*10 + i];

    int jidx[4];
    jidx[0] = 0; jidx[1] = ch*3 + 1; jidx[2] = ch*3 + 2; jidx[3] = ch*3 + 3;
    float J[4][3];
#pragma unroll
    for (int q = 0; q < 4; ++q) {
        int j = jidx[q];
#pragma unroll
        for (int c = 0; c < 3; ++c) {
            float acc = sS[480 + j*3 + c];
#pragma unroll
            for (int qq = 0; qq < 10; ++qq)
                acc = fmaf(b[qq], sS[qq*48 + j*3 + c], acc);
            J[q][c] = acc;
        }
    }

    const float* Rn = Rs + (size_t)n * 144;
    float* An = Aws + (size_t)n * 192;

    float GpR[9], Gpt[3];
#pragma unroll
    for (int r = 0; r < 3; ++r) {
        GpR[r*3+0] =  Rn[r*3+0];
        GpR[r*3+1] = -Rn[r*3+1];
        GpR[r*3+2] = -Rn[r*3+2];
    }
    Gpt[0] = J[0][0]; Gpt[1] = J[0][1]; Gpt[2] = J[0][2];

    if (ch == 0) {
#pragma unroll
        for (int r = 0; r < 3; ++r) {
            float rel = GpR[r*3+0]*J[0][0] + GpR[r*3+1]*J[0][1] + GpR[r*3+2]*J[0][2];
            An[r*4 + 0] = GpR[r*3+0];
            An[r*4 + 1] = GpR[r*3+1];
            An[r*4 + 2] = GpR[r*3+2];
            An[r*4 + 3] = Gpt[r] - rel;
        }
    }

#pragma unroll
    for (int st = 0; st < 3; ++st) {
        int i = jidx[st+1];
        const float* Ri = Rn + (size_t)i * 9;
        float t0 = J[st+1][0] - J[st][0];
        float t1 = J[st+1][1] - J[st][1];
        float t2 = J[st+1][2] - J[st][2];
        float GR[9], Gt[3];
#pragma unroll
        for (int r = 0; r < 3; ++r) {
#pragma unroll
            for (int c = 0; c < 3; ++c)
                GR[r*3+c] = GpR[r*3+0]*Ri[c] + GpR[r*3+1]*Ri[3+c] + GpR[r*3+2]*Ri[6+c];
            Gt[r] = GpR[r*3+0]*t0 + GpR[r*3+1]*t1 + GpR[r*3+2]*t2 + Gpt[r];
        }
#pragma unroll
        for (int r = 0; r < 3; ++r) {
            float rel = GR[r*3+0]*J[st+1][0] + GR[r*3+1]*J[st+1][1] + GR[r*3+2]*J[st+1][2];
            An[i*12 + r*4 + 0] = GR[r*3+0];
            An[i*12 + r*4 + 1] = GR[r*3+1];
            An[i*12 + r*4 + 2] = GR[r*3+2];
            An[i*12 + r*4 + 3] = Gt[r] - rel;
        }
#pragma unroll
        for (int r = 0; r < 9; ++r) GpR[r] = GR[r];
        Gpt[0] = Gt[0]; Gpt[1] = Gt[1]; Gpt[2] = Gt[2];
    }
}

// ---------------- K34: MFMA GEMM (384 cols) + blend (scalar-A, 2x amortized)
// + partial joints (atomics). Block = 16 samples x 384 cols (= 128 verts).
// Wave w: 6 col-subtiles (cols w*96 .. w*96+95). grid (N/16, 7).
__global__ __launch_bounds__(256, 1) void k34_gemm_blend(
    const bf16x8* __restrict__ Af,      // [(N/16)][5][64]
    const bf16x8* __restrict__ Bf,      // [NTB][5][64]
    const float* __restrict__ vtemp,
    const float* __restrict__ Aws,
    const float* __restrict__ weights,
    const float* __restrict__ Jreg,
    float* __restrict__ verts,
    float* __restrict__ joints,         // accumulated via atomicAdd
    int N)
{
    __shared__ __attribute__((aligned(16))) float sC[16 * 386];
#define SCg(r_, c_) sC[(r_) * 386 + (c_)]
    const int tid  = threadIdx.x;
    const int w    = tid >> 6;
    const int lane = tid & 63;
    const int mt   = blockIdx.x;                 // 16 samples
    const int ntb0 = blockIdx.y * 24 + w * 6;    // wave's first B n-tile

    f32x4 acc0 = {0.f,0.f,0.f,0.f};
    f32x4 acc1 = {0.f,0.f,0.f,0.f};
    f32x4 acc2 = {0.f,0.f,0.f,0.f};
    f32x4 acc3 = {0.f,0.f,0.f,0.f};
    f32x4 acc4 = {0.f,0.f,0.f,0.f};
    f32x4 acc5 = {0.f,0.f,0.f,0.f};

    const bf16x8* Ab = Af + (size_t)mt * 5 * 64 + lane;
    const bf16x8* Bb = Bf + lane;

#pragma unroll
    for (int ks = 0; ks < 5; ++ks) {
        bf16x8 a  = Ab[ks * 64];
        bf16x8 b0 = Bb[((size_t)(ntb0+0) * 5 + ks) * 64];
        bf16x8 b1 = Bb[((size_t)(ntb0+1) * 5 + ks) * 64];
        bf16x8 b2 = Bb[((size_t)(ntb0+2) * 5 + ks) * 64];
        bf16x8 b3 = Bb[((size_t)(ntb0+3) * 5 + ks) * 64];
        bf16x8 b4 = Bb[((size_t)(ntb0+4) * 5 + ks) * 64];
        bf16x8 b5 = Bb[((size_t)(ntb0+5) * 5 + ks) * 64];
        acc0 = __builtin_amdgcn_mfma_f32_16x16x32_bf16(a, b0, acc0, 0, 0, 0);
        acc1 = __builtin_amdgcn_mfma_f32_16x16x32_bf16(a, b1, acc1, 0, 0, 0);
        acc2 = __builtin_amdgcn_mfma_f32_16x16x32_bf16(a, b2, acc2, 0, 0, 0);
        acc3 = __builtin_amdgcn_mfma_f32_16x16x32_bf16(a, b3, acc3, 0, 0, 0);
        acc4 = __builtin_amdgcn_mfma_f32_16x16x32_bf16(a, b4, acc4, 0, 0, 0);
        acc5 = __builtin_amdgcn_mfma_f32_16x16x32_bf16(a, b5, acc5, 0, 0, 0);
    }

    // C/D layout: col = lane&15, row = (lane>>4)*4 + r  [m89-verified]
    {
        const int rl = (lane >> 4) * 4;
        const int cl = w * 96 + (lane & 15);
#pragma unroll
        for (int r = 0; r < 4; ++r) {
            SCg(rl + r, cl +  0) = acc0[r];
            SCg(rl + r, cl + 16) = acc1[r];
            SCg(rl + r, cl + 32) = acc2[r];
            SCg(rl + r, cl + 48) = acc3[r];
            SCg(rl + r, cl + 64) = acc4[r];
            SCg(rl + r, cl + 80) = acc5[r];
        }
    }
    __syncthreads();

    // ---- blend phase: scalar-A (s_load), amortized over 2 vert groups
    const int vgA = blockIdx.y * 128 + lane;         // group 0 vert
    const int vgB = vgA + 64;                        // group 1 vert
    const bool valA = vgA < NV;
    const bool valB = vgB < NV;
    const int cvA = valA ? vgA : (NV - 1);
    const int cvB = valB ? vgB : (NV - 1);

    const float4* wrA = reinterpret_cast<const float4*>(&weights[(size_t)cvA * 16]);
    const float4* wrB = reinterpret_cast<const float4*>(&weights[(size_t)cvB * 16]);
    float vtxA = vtemp[cvA*3+0], vtyA = vtemp[cvA*3+1], vtzA = vtemp[cvA*3+2];
    float vtxB = vtemp[cvB*3+0], vtyB = vtemp[cvB*3+1], vtzB = vtemp[cvB*3+2];

    float res[24];
#pragma unroll
    for (int it = 0; it < 4; ++it) {
        const int nl = w * 4 + it;
        const int n  = __builtin_amdgcn_readfirstlane(mt * 16 + nl);
        const float* An = Aws + (size_t)n * 192;     // uniform -> s_load path

        float pxA = SCg(nl, lane*3 + 0) + vtxA;
        float pyA = SCg(nl, lane*3 + 1) + vtyA;
        float pzA = SCg(nl, lane*3 + 2) + vtzA;
        float pxB = SCg(nl, 192 + lane*3 + 0) + vtxB;
        float pyB = SCg(nl, 192 + lane*3 + 1) + vtyB;
        float pzB = SCg(nl, 192 + lane*3 + 2) + vtzB;

        float oxA=0.f, oyA=0.f, ozA=0.f, oxB=0.f, oyB=0.f, ozB=0.f;
#pragma unroll
        for (int q = 0; q < 4; ++q) {
            float4 wqA = wrA[q];
            float4 wqB = wrB[q];
#define BJQ2(jj_, wwA_, wwB_) { \
            const float* ap = An + (4*q + jj_) * 12; \
            float a0=ap[0], a1=ap[1], a2 =ap[2],  a3 =ap[3]; \
            float a4=ap[4], a5=ap[5], a6 =ap[6],  a7 =ap[7]; \
            float a8=ap[8], a9=ap[9], a10=ap[10], a11=ap[11]; \
            float X = fmaf(a0,pxA, fmaf(a1,pyA, fmaf(a2,pzA, a3))); \
            float Y = fmaf(a4,pxA, fmaf(a5,pyA, fmaf(a6,pzA, a7))); \
            float Z = fmaf(a8,pxA, fmaf(a9,pyA, fmaf(a10,pzA, a11))); \
            oxA = fmaf(wwA_, X, oxA); oyA = fmaf(wwA_, Y, oyA); ozA = fmaf(wwA_, Z, ozA); \
            X = fmaf(a0,pxB, fmaf(a1,pyB, fmaf(a2,pzB, a3))); \
            Y = fmaf(a4,pxB, fmaf(a5,pyB, fmaf(a6,pzB, a7))); \
            Z = fmaf(a8,pxB, fmaf(a9,pyB, fmaf(a10,pzB, a11))); \
            oxB = fmaf(wwB_, X, oxB); oyB = fmaf(wwB_, Y, oyB); ozB = fmaf(wwB_, Z, ozB); }
            BJQ2(0, wqA.x, wqB.x) BJQ2(1, wqA.y, wqB.y)
            BJQ2(2, wqA.z, wqB.z) BJQ2(3, wqA.w, wqB.w)
#undef BJQ2
        }
        res[it*6+0] = oxA; res[it*6+1] = oyA; res[it*6+2] = ozA;
        res[it*6+3] = oxB; res[it*6+4] = oyB; res[it*6+5] = ozB;
    }
    __syncthreads();   // all blend reads of sC complete

    // write blended verts to global and back into sC for the joint pass
#pragma unroll
    for (int it = 0; it < 4; ++it) {
        const int nl = w * 4 + it;
        SCg(nl, lane*3 + 0)       = valA ? res[it*6+0] : 0.f;
        SCg(nl, lane*3 + 1)       = valA ? res[it*6+1] : 0.f;
        SCg(nl, lane*3 + 2)       = valA ? res[it*6+2] : 0.f;
        SCg(nl, 192 + lane*3 + 0) = valB ? res[it*6+3] : 0.f;
        SCg(nl, 192 + lane*3 + 1) = valB ? res[it*6+4] : 0.f;
        SCg(nl, 192 + lane*3 + 2) = valB ? res[it*6+5] : 0.f;
        if (valA) {
            float* o = verts + (size_t)(mt*16 + nl) * M3 + (size_t)vgA * 3;
            o[0] = res[it*6+0]; o[1] = res[it*6+1]; o[2] = res[it*6+2];
        }
        if (valB) {
            float* o = verts + (size_t)(mt*16 + nl) * M3 + (size_t)vgB * 3;
            o[0] = res[it*6+3]; o[1] = res[it*6+4]; o[2] = res[it*6+5];
        }
    }
    __syncthreads();

    // ---- partial joints: task (s = tid>>4, j = tid&15); reduce 128 verts
    {
        const int s  = tid >> 4;
        const int j  = tid & 15;
        const int vb = blockIdx.y * 128;
        float a0 = 0.f, a1 = 0.f, a2 = 0.f;
#pragma unroll 4
        for (int v = 0; v < 128; ++v) {
            float jr = (vb + v < NV) ? Jreg[(size_t)(vb + v) * 16 + j] : 0.f;
            a0 = fmaf(jr, SCg(s, v*3 + 0), a0);
            a1 = fmaf(jr, SCg(s, v*3 + 1), a1);
            a2 = fmaf(jr, SCg(s, v*3 + 2), a2);
        }
        float* jp = joints + (size_t)(mt * 16 + s) * 48 + j * 3;
        atomicAdd(&jp[0], a0);
        atomicAdd(&jp[1], a1);
        atomicAdd(&jp[2], a2);
    }
#undef SCg
}

extern "C" void kernel_launch(void* const* d_in, const int* in_sizes, int n_in,
                              void* d_out, int out_size, void* d_ws, size_t ws_size,
                              hipStream_t stream)
{
    const float* beta   = (const float*)d_in[0];
    const float* theta  = (const float*)d_in[1];
    const float* vtemp  = (const float*)d_in[2];
    const float* shaped = (const float*)d_in[3];
    const float* Jreg   = (const float*)d_in[4];
    const float* posed  = (const float*)d_in[5];
    const float* wts    = (const float*)d_in[6];
    float* out = (float*)d_out;
    const int N = in_sizes[0] / 10;   // 4096

    float* verts  = out;                            // N*2334
    float* joints = out + (size_t)N * M3;           // N*48
    float* RsOut  = joints + (size_t)N * 48;        // N*144
    float* Aws    = (float*)d_ws;                   // N*192
    float*  fbase = Aws + (size_t)N * 192;
    const int nA = (N / 16) * 5 * 64;
    const int nB = NTB * 5 * 64;
    bf16x8* Af    = (bf16x8*)fbase;                      // nA * 16B
    bf16x8* Bf    = (bf16x8*)(fbase + (size_t)nA * 4);   // nB * 16B
    float*  sjjt  = fbase + (size_t)nA * 4 + (size_t)nB * 4;  // 528 floats

    const int rodBlocks = (N * NJ) / 256;
    const int zeroBlocks = (N * 48 + 255) / 256;

    k01_prep<<<44 + rodBlocks + nB/256 + nA/256, 256, 0, stream>>>(
        shaped, posed, Jreg, vtemp, theta, beta, sjjt, RsOut, Bf, Af, N);
    k2c_chain<<<(N*5 + 255)/256 + zeroBlocks, 256, 0, stream>>>(
        beta, RsOut, sjjt, Aws, joints, N);
    k34_gemm_blend<<<dim3(N/16, 7), 256, 0, stream>>>(
        Af, Bf, vtemp, Aws, wts, Jreg, verts, joints, N);
}

// Round 29
// 69.857 us; speedup vs baseline: 1.2259x; 1.2259x over previous
//
#include <hip/hip_runtime.h>
#include <math.h>

#define NJ 16
#define NV 778
#define M3 2334   // NV*3
#define NTB 156   // B n-tiles: 13 col-blocks x 12 subtiles

typedef float f32x4  __attribute__((ext_vector_type(4)));
typedef short bf16x8 __attribute__((ext_vector_type(8)));

__device__ __forceinline__ unsigned short f2bf(float x) {
    unsigned int u = __float_as_uint(x);
    unsigned int r = (u + 0x7FFF + ((u >> 16) & 1)) >> 16;   // RNE
    return (unsigned short)r;
}

__device__ __forceinline__ void rodrigues9(
    float t0, float t1, float t2,
    float& r0, float& r1, float& r2, float& r3, float& r4,
    float& r5, float& r6, float& r7, float& r8)
{
    const float eps = 1e-8f;
    float a0 = t0 + eps, a1 = t1 + eps, a2 = t2 + eps;
    float angle = sqrtf(a0*a0 + a1*a1 + a2*a2);
    float inv  = 1.0f / angle;
    float half = 0.5f * angle;
    float sh = sinf(half), chh = cosf(half);
    float qw = chh;
    float qx = sh * t0 * inv;
    float qy = sh * t1 * inv;
    float qz = sh * t2 * inv;
    float qn = 1.0f / sqrtf(qw*qw + qx*qx + qy*qy + qz*qz);
    qw *= qn; qx *= qn; qy *= qn; qz *= qn;
    float w2=qw*qw, x2=qx*qx, y2=qy*qy, z2=qz*qz;
    float wx=qw*qx, wy=qw*qy, wz=qw*qz;
    float xy=qx*qy, xz=qx*qz, yz=qy*qz;
    r0 = w2 + x2 - y2 - z2;
    r1 = 2.f*(xy - wz);
    r2 = 2.f*(wy + xz);
    r3 = 2.f*(wz + xy);
    r4 = w2 - x2 + y2 - z2;
    r5 = 2.f*(yz - wx);
    r6 = 2.f*(xz - wy);
    r7 = 2.f*(wx + yz);
    r8 = w2 - x2 - y2 + z2;
}

// d_out layout (floats): verts [N*2334] | joints [N*48] | Rs [N*144]
// d_ws layout (floats):  A [N*192] | Afrag | Bfrag | SJJT(528)
// Pipeline (3 launches):
//   k01{SJJT->ws + Rodrigues->Rs + B-frags + A-frags(inline Rodrigues)}
//   -> k2c{kinematic chain -> Aws; zero joints}
//   -> k34{MFMA GEMM + LBS blend + per-block partial joints -> atomicAdd}
//
// LAUNCH-BOUNDS LESSON (R4,R8): second arg w caps VGPR at 256/w -> only (B,1).
// LATENCY LESSONS (R9-R28): (a) multi-barrier per-sample blocks serialize;
// (b) wave-uniform data -> scalar pipe, only from a PRIOR kernel (R23);
// vector-A regressed (R27: vector-pipe contention); (c) matmul K>=16 -> MFMA;
// (d) dependent launches ~3us; (e) fuse producer->consumer through LDS;
// (f) wider tiles trade occupancy for load amortization at a LOSS here
// (R28: 25KB LDS -> 25% occupancy -> -23%). R26 config = local optimum.

// ---------------- K01: SJ/JT reductions + Rodrigues + B-frags + A-frags.
__global__ __launch_bounds__(256, 1) void k01_prep(
    const float* __restrict__ shapedirs,
    const float* __restrict__ posedirs,
    const float* __restrict__ Jreg,
    const float* __restrict__ vtemp,
    const float* __restrict__ theta,
    const float* __restrict__ beta,
    float* __restrict__ SJJT,     // ws, 528 floats
    float* __restrict__ RsOut,
    bf16x8* __restrict__ Bf,
    bf16x8* __restrict__ Af,
    int N)
{
    const int tid = threadIdx.x;
    const int rodBlocks = (N * NJ) / 256;        // 256
    const int nB = NTB * 5 * 64;                 // 49920
    const int bfBlocks = nB / 256;               // 195
    if (blockIdx.x < 44) {
        int task = blockIdx.x * 4 + (tid >> 6);   // 0..175
        int lane = tid & 63;
        if (task < 176) {
            int b = task >> 4;      // 0..10
            int j = task & 15;
            const float* src = (b < 10) ? (shapedirs + (size_t)b * M3) : vtemp;
            float a0 = 0.f, a1 = 0.f, a2 = 0.f;
            for (int v = lane; v < NV; v += 64) {
                float jr = Jreg[v * 16 + j];
                a0 = fmaf(src[v*3 + 0], jr, a0);
                a1 = fmaf(src[v*3 + 1], jr, a1);
                a2 = fmaf(src[v*3 + 2], jr, a2);
            }
#pragma unroll
            for (int m = 1; m < 64; m <<= 1) {
                a0 += __shfl_xor(a0, m);
                a1 += __shfl_xor(a1, m);
                a2 += __shfl_xor(a2, m);
            }
            if (lane == 0) {
                int base = (b < 10) ? (b*48 + j*3) : (480 + j*3);
                SJJT[base + 0] = a0;
                SJJT[base + 1] = a1;
                SJJT[base + 2] = a2;
            }
        }
        return;
    }
    if (blockIdx.x < 44 + rodBlocks) {
        int idx = (blockIdx.x - 44) * 256 + tid;
        int n = idx >> 4;
        int j = idx & 15;
        float r0,r1,r2,r3,r4,r5,r6,r7,r8;
        rodrigues9(theta[n*48 + j*3 + 0], theta[n*48 + j*3 + 1],
                   theta[n*48 + j*3 + 2], r0,r1,r2,r3,r4,r5,r6,r7,r8);
        float* R = RsOut + (size_t)idx * 9;
        R[0]=r0; R[1]=r1; R[2]=r2; R[3]=r3; R[4]=r4;
        R[5]=r5; R[6]=r6; R[7]=r7; R[8]=r8;
        return;
    }
    if (blockIdx.x < 44 + rodBlocks + bfBlocks) {
        int idx = (blockIdx.x - 44 - rodBlocks) * 256 + tid;
        int lane = idx & 63;
        int ks   = (idx >> 6) % 5;
        int nt   = idx / 320;
        int col = nt * 16 + (lane & 15);
        int k0  = ks * 32 + (lane >> 4) * 8;
        bf16x8 o;
#pragma unroll
        for (int j = 0; j < 8; ++j) {
            int k = k0 + j;
            float val = 0.f;
            if (col < M3) {
                if (k < 10)       val = shapedirs[(size_t)k * M3 + col];
                else if (k < 145) val = posedirs[(size_t)(k - 10) * M3 + col];
            }
            o[j] = (short)f2bf(val);
        }
        Bf[idx] = o;
        return;
    }
    // A-frag packing with INLINE Rodrigues (validated R23/R24)
    int idx = (blockIdx.x - 44 - rodBlocks - bfBlocks) * 256 + tid;
    int nA = (N / 16) * 5 * 64;
    if (idx >= nA) return;
    int lane = idx & 63;
    int ks   = (idx >> 6) % 5;
    int mt   = idx / 320;
    int n  = mt * 16 + (lane & 15);
    int k0 = ks * 32 + (lane >> 4) * 8;

    int kkA = k0 - 10;
    int jA  = (kkA < 0) ? 0 : (kkA > 134 ? 14 : kkA / 9);
    int kkB = k0 - 3;
    int jB  = (kkB < 0) ? 0 : (kkB > 134 ? 14 : kkB / 9);

    float ra0,ra1,ra2,ra3,ra4,ra5,ra6,ra7,ra8;
    rodrigues9(theta[n*48 + (jA+1)*3 + 0], theta[n*48 + (jA+1)*3 + 1],
               theta[n*48 + (jA+1)*3 + 2], ra0,ra1,ra2,ra3,ra4,ra5,ra6,ra7,ra8);
    float rb0,rb1,rb2,rb3,rb4,rb5,rb6,rb7,rb8;
    rodrigues9(theta[n*48 + (jB+1)*3 + 0], theta[n*48 + (jB+1)*3 + 1],
               theta[n*48 + (jB+1)*3 + 2], rb0,rb1,rb2,rb3,rb4,rb5,rb6,rb7,rb8);

    bf16x8 o;
#pragma unroll
    for (int j = 0; j < 8; ++j) {
        int k = k0 + j;
        float val;
        if (k < 10) {
            val = beta[(size_t)n * 10 + k];
        } else if (k < 145) {
            int kk = k - 10;
            int jj = kk / 9;
            int rr = kk - jj * 9;
            float sa = (rr==0)?ra0:(rr==1)?ra1:(rr==2)?ra2:(rr==3)?ra3:
                       (rr==4)?ra4:(rr==5)?ra5:(rr==6)?ra6:(rr==7)?ra7:ra8;
            float sb = (rr==0)?rb0:(rr==1)?rb1:(rr==2)?rb2:(rr==3)?rb3:
                       (rr==4)?rb4:(rr==5)?rb5:(rr==6)?rb6:(rr==7)?rb7:rb8;
            float vv = (jj == jA) ? sa : sb;
            if ((rr & 3) == 0) vv -= 1.f;
            val = vv;
        } else {
            val = 0.f;
        }
        o[j] = (short)f2bf(val);
    }
    Af[idx] = o;
}

// ---------------- K2C: kinematic chain -> Aws; zero joints for k34 atomics.
__global__ __launch_bounds__(256, 1) void k2c_chain(
    const float* __restrict__ beta,
    const float* __restrict__ Rs,
    const float* __restrict__ SJJT,   // ws
    float* __restrict__ Aws,
    float* __restrict__ joints,       // zeroed here
    int N)
{
    const int tid = threadIdx.x;
    const int KB = (N * 5 + 255) / 256;          // 80
    if (blockIdx.x >= KB) {
        int idx = (blockIdx.x - KB) * 256 + tid;
        if (idx < N * 48) joints[idx] = 0.f;
        return;
    }
    __shared__ float sS[528];
    for (int i = tid; i < 528; i += 256) sS[i] = SJJT[i];
    __syncthreads();
    int gid = blockIdx.x * 256 + tid;
    if (gid >= N * 5) return;
    int n  = gid / 5;
    int ch = gid % 5;

    float b[10];
#pragma unroll
    for (int i = 0; i < 10; ++i) b[i] = beta[n*10 + i];

    int jidx[4];
    jidx[0] = 0; jidx[1] = ch*3 + 1; jidx[2] = ch*3 + 2; jidx[3] = ch*3 + 3;
    float J[4][3];
#pragma unroll
    for (int q = 0; q < 4; ++q) {
        int j = jidx[q];
#pragma unroll
        for (int c = 0; c < 3; ++c) {
            float acc = sS[480 + j*3 + c];
#pragma unroll
            for (int qq = 0; qq < 10; ++qq)
                acc = fmaf(b[qq], sS[qq*48 + j*3 + c], acc);
            J[q][c] = acc;
        }
    }

    const float* Rn = Rs + (size_t)n * 144;
    float* An = Aws + (size_t)n * 192;

    float GpR[9], Gpt[3];
#pragma unroll
    for (int r = 0; r < 3; ++r) {
        GpR[r*3+0] =  Rn[r*3+0];
        GpR[r*3+1] = -Rn[r*3+1];
        GpR[r*3+2] = -Rn[r*3+2];
    }
    Gpt[0] = J[0][0]; Gpt[1] = J[0][1]; Gpt[2] = J[0][2];

    if (ch == 0) {
#pragma unroll
        for (int r = 0; r < 3; ++r) {
            float rel = GpR[r*3+0]*J[0][0] + GpR[r*3+1]*J[0][1] + GpR[r*3+2]*J[0][2];
            An[r*4 + 0] = GpR[r*3+0];
            An[r*4 + 1] = GpR[r*3+1];
            An[r*4 + 2] = GpR[r*3+2];
            An[r*4 + 3] = Gpt[r] - rel;
        }
    }

#pragma unroll
    for (int st = 0; st < 3; ++st) {
        int i = jidx[st+1];
        const float* Ri = Rn + (size_t)i * 9;
        float t0 = J[st+1][0] - J[st][0];
        float t1 = J[st+1][1] - J[st][1];
        float t2 = J[st+1][2] - J[st][2];
        float GR[9], Gt[3];
#pragma unroll
        for (int r = 0; r < 3; ++r) {
#pragma unroll
            for (int c = 0; c < 3; ++c)
                GR[r*3+c] = GpR[r*3+0]*Ri[c] + GpR[r*3+1]*Ri[3+c] + GpR[r*3+2]*Ri[6+c];
            Gt[r] = GpR[r*3+0]*t0 + GpR[r*3+1]*t1 + GpR[r*3+2]*t2 + Gpt[r];
        }
#pragma unroll
        for (int r = 0; r < 3; ++r) {
            float rel = GR[r*3+0]*J[st+1][0] + GR[r*3+1]*J[st+1][1] + GR[r*3+2]*J[st+1][2];
            An[i*12 + r*4 + 0] = GR[r*3+0];
            An[i*12 + r*4 + 1] = GR[r*3+1];
            An[i*12 + r*4 + 2] = GR[r*3+2];
            An[i*12 + r*4 + 3] = Gt[r] - rel;
        }
#pragma unroll
        for (int r = 0; r < 9; ++r) GpR[r] = GR[r];
        Gpt[0] = Gt[0]; Gpt[1] = Gt[1]; Gpt[2] = Gt[2];
    }
}

// ---------------- K34: MFMA GEMM + LBS blend + partial joints (atomics).
__global__ __launch_bounds__(256, 1) void k34_gemm_blend(
    const bf16x8* __restrict__ Af,      // [(N/16)][5][64]
    const bf16x8* __restrict__ Bf,      // [NTB][5][64]
    const float* __restrict__ vtemp,
    const float* __restrict__ Aws,
    const float* __restrict__ weights,
    const float* __restrict__ Jreg,
    float* __restrict__ verts,
    float* __restrict__ joints,         // accumulated via atomicAdd
    int N)
{
    __shared__ float sC[16][194];
    const int tid  = threadIdx.x;
    const int w    = tid >> 6;
    const int lane = tid & 63;
    const int mt   = blockIdx.x;                 // 16 samples
    const int ntb  = blockIdx.y * 12 + w * 3;    // B n-tile base for this wave

    f32x4 acc0 = {0.f,0.f,0.f,0.f};
    f32x4 acc1 = {0.f,0.f,0.f,0.f};
    f32x4 acc2 = {0.f,0.f,0.f,0.f};

    const bf16x8* Ab = Af + (size_t)mt * 5 * 64 + lane;
    const bf16x8* Bb = Bf + lane;

#pragma unroll
    for (int ks = 0; ks < 5; ++ks) {
        bf16x8 a  = Ab[ks * 64];
        bf16x8 b0 = Bb[((size_t)(ntb+0) * 5 + ks) * 64];
        bf16x8 b1 = Bb[((size_t)(ntb+1) * 5 + ks) * 64];
        bf16x8 b2 = Bb[((size_t)(ntb+2) * 5 + ks) * 64];
        acc0 = __builtin_amdgcn_mfma_f32_16x16x32_bf16(a, b0, acc0, 0, 0, 0);
        acc1 = __builtin_amdgcn_mfma_f32_16x16x32_bf16(a, b1, acc1, 0, 0, 0);
        acc2 = __builtin_amdgcn_mfma_f32_16x16x32_bf16(a, b2, acc2, 0, 0, 0);
    }

    // C/D layout: col = lane&15, row = (lane>>4)*4 + r  [m89-verified]
    {
        const int rl = (lane >> 4) * 4;
        const int cl = w * 48 + (lane & 15);
#pragma unroll
        for (int r = 0; r < 4; ++r) {
            sC[rl + r][cl +  0] = acc0[r];
            sC[rl + r][cl + 16] = acc1[r];
            sC[rl + r][cl + 32] = acc2[r];
        }
    }
    __syncthreads();

    // ---- blend phase (read sC, hold results in regs)
    const int vg = blockIdx.y * 64 + lane;
    const bool valid = vg < NV;
    const int cvg = valid ? vg : (NV - 1);

    const float4* wrow = reinterpret_cast<const float4*>(&weights[(size_t)cvg * 16]);
    float vtx = vtemp[cvg*3 + 0];
    float vty = vtemp[cvg*3 + 1];
    float vtz = vtemp[cvg*3 + 2];

    float res[12];
#pragma unroll
    for (int it = 0; it < 4; ++it) {
        const int nl = w * 4 + it;
        const int n  = __builtin_amdgcn_readfirstlane(mt * 16 + nl);
        const float* An = Aws + (size_t)n * 192;     // uniform -> s_load path

        float px = sC[nl][lane*3 + 0] + vtx;
        float py = sC[nl][lane*3 + 1] + vty;
        float pz = sC[nl][lane*3 + 2] + vtz;

        float ox = 0.f, oy = 0.f, oz = 0.f;
#pragma unroll
        for (int q = 0; q < 4; ++q) {
            float4 wq = wrow[q];
#define BJQ(jj_, ww_) { \
            const float* ap = An + (4*q + jj_) * 12; \
            float a0=ap[0], a1=ap[1], a2 =ap[2],  a3 =ap[3]; \
            float a4=ap[4], a5=ap[5], a6 =ap[6],  a7 =ap[7]; \
            float a8=ap[8], a9=ap[9], a10=ap[10], a11=ap[11]; \
            float X = fmaf(a0,px, fmaf(a1,py, fmaf(a2,pz, a3))); \
            float Y = fmaf(a4,px, fmaf(a5,py, fmaf(a6,pz, a7))); \
            float Z = fmaf(a8,px, fmaf(a9,py, fmaf(a10,pz, a11))); \
            ox = fmaf(ww_, X, ox); oy = fmaf(ww_, Y, oy); oz = fmaf(ww_, Z, oz); }
            BJQ(0, wq.x) BJQ(1, wq.y) BJQ(2, wq.z) BJQ(3, wq.w)
#undef BJQ
        }
        res[it*3+0] = ox; res[it*3+1] = oy; res[it*3+2] = oz;
    }
    __syncthreads();   // all blend reads of sC complete

    // write blended verts to global and back into sC for the joint pass
#pragma unroll
    for (int it = 0; it < 4; ++it) {
        const int nl = w * 4 + it;
        sC[nl][lane*3 + 0] = res[it*3+0];
        sC[nl][lane*3 + 1] = res[it*3+1];
        sC[nl][lane*3 + 2] = res[it*3+2];
        if (valid) {
            float* o = verts + (size_t)(mt*16 + nl) * M3 + (size_t)vg * 3;
            o[0] = res[it*3+0]; o[1] = res[it*3+1]; o[2] = res[it*3+2];
        }
    }
    __syncthreads();

    // ---- partial joints: task (s = tid>>4, j = tid&15); reduce 64 verts
    {
        const int s  = tid >> 4;
        const int j  = tid & 15;
        const int vb = blockIdx.y * 64;
        float a0 = 0.f, a1 = 0.f, a2 = 0.f;
#pragma unroll 4
        for (int v = 0; v < 64; ++v) {
            float jr = (vb + v < NV) ? Jreg[(size_t)(vb + v) * 16 + j] : 0.f;
            a0 = fmaf(jr, sC[s][v*3 + 0], a0);
            a1 = fmaf(jr, sC[s][v*3 + 1], a1);
            a2 = fmaf(jr, sC[s][v*3 + 2], a2);
        }
        float* jp = joints + (size_t)(mt * 16 + s) * 48 + j * 3;
        atomicAdd(&jp[0], a0);
        atomicAdd(&jp[1], a1);
        atomicAdd(&jp[2], a2);
    }
}

extern "C" void kernel_launch(void* const* d_in, const int* in_sizes, int n_in,
                              void* d_out, int out_size, void* d_ws, size_t ws_size,
                              hipStream_t stream)
{
    const float* beta   = (const float*)d_in[0];
    const float* theta  = (const float*)d_in[1];
    const float* vtemp  = (const float*)d_in[2];
    const float* shaped = (const float*)d_in[3];
    const float* Jreg   = (const float*)d_in[4];
    const float* posed  = (const float*)d_in[5];
    const float* wts    = (const float*)d_in[6];
    float* out = (float*)d_out;
    const int N = in_sizes[0] / 10;   // 4096

    float* verts  = out;                            // N*2334
    float* joints = out + (size_t)N * M3;           // N*48
    float* RsOut  = joints + (size_t)N * 48;        // N*144
    float* Aws    = (float*)d_ws;                   // N*192
    float*  fbase = Aws + (size_t)N * 192;
    const int nA = (N / 16) * 5 * 64;
    const int nB = NTB * 5 * 64;
    bf16x8* Af    = (bf16x8*)fbase;                      // nA * 16B
    bf16x8* Bf    = (bf16x8*)(fbase + (size_t)nA * 4);   // nB * 16B
    float*  sjjt  = fbase + (size_t)nA * 4 + (size_t)nB * 4;  // 528 floats

    const int rodBlocks = (N * NJ) / 256;
    const int zeroBlocks = (N * 48 + 255) / 256;

    k01_prep<<<44 + rodBlocks + nB/256 + nA/256, 256, 0, stream>>>(
        shaped, posed, Jreg, vtemp, theta, beta, sjjt, RsOut, Bf, Af, N);
    k2c_chain<<<(N*5 + 255)/256 + zeroBlocks, 256, 0, stream>>>(
        beta, RsOut, sjjt, Aws, joints, N);
    k34_gemm_blend<<<dim3(N/16, 13), 256, 0, stream>>>(
        Af, Bf, vtemp, Aws, wts, Jreg, verts, joints, N);
}

// Round 30
// 69.553 us; speedup vs baseline: 1.2312x; 1.0044x over previous
//
#include <hip/hip_runtime.h>
#include <math.h>

#define NJ 16
#define NV 778
#define M3 2334   // NV*3
#define NTB 156   // B n-tiles: 13 col-blocks x 12 subtiles

typedef float f32x4  __attribute__((ext_vector_type(4)));
typedef short bf16x8 __attribute__((ext_vector_type(8)));

__device__ __forceinline__ unsigned short f2bf(float x) {
    unsigned int u = __float_as_uint(x);
    unsigned int r = (u + 0x7FFF + ((u >> 16) & 1)) >> 16;   // RNE
    return (unsigned short)r;
}

__device__ __forceinline__ void rodrigues9(
    float t0, float t1, float t2,
    float& r0, float& r1, float& r2, float& r3, float& r4,
    float& r5, float& r6, float& r7, float& r8)
{
    const float eps = 1e-8f;
    float a0 = t0 + eps, a1 = t1 + eps, a2 = t2 + eps;
    float angle = sqrtf(a0*a0 + a1*a1 + a2*a2);
    float inv  = 1.0f / angle;
    float half = 0.5f * angle;
    float sh = sinf(half), chh = cosf(half);
    float qw = chh;
    float qx = sh * t0 * inv;
    float qy = sh * t1 * inv;
    float qz = sh * t2 * inv;
    float qn = 1.0f / sqrtf(qw*qw + qx*qx + qy*qy + qz*qz);
    qw *= qn; qx *= qn; qy *= qn; qz *= qn;
    float w2=qw*qw, x2=qx*qx, y2=qy*qy, z2=qz*qz;
    float wx=qw*qx, wy=qw*qy, wz=qw*qz;
    float xy=qx*qy, xz=qx*qz, yz=qy*qz;
    r0 = w2 + x2 - y2 - z2;
    r1 = 2.f*(xy - wz);
    r2 = 2.f*(wy + xz);
    r3 = 2.f*(wz + xy);
    r4 = w2 - x2 + y2 - z2;
    r5 = 2.f*(yz - wx);
    r6 = 2.f*(xz - wy);
    r7 = 2.f*(wx + yz);
    r8 = w2 - x2 - y2 + z2;
}

// d_out layout (floats): verts [N*2334] | joints [N*48] | Rs [N*144]
// d_ws layout (floats):  A [N*192] | Afrag | Bfrag | SJJT(528)
// Pipeline (3 launches):
//   k01{SJJT->ws + Rodrigues->Rs + B-frags + A-frags(inline Rodrigues)}
//   -> k2c{kinematic chain -> Aws; zero joints}
//   -> k34{MFMA GEMM + LBS blend + partial joints (b128 c-major LDS) -> atomics}
//
// LAUNCH-BOUNDS LESSON (R4,R8): second arg w caps VGPR at 256/w -> only (B,1).
// LATENCY LESSONS (R9-R29): (a) multi-barrier per-sample blocks serialize;
// (b) wave-uniform data -> scalar pipe, only from a PRIOR kernel (R23);
// vector-A regressed (R27); (c) matmul K>=16 -> MFMA; (d) dependent launches
// ~3us; (e) fuse producer->consumer through LDS; (f) effective LDS budget is
// ~64KB/CU here (R28: 25KB -> 2 blocks/CU -> -23%); (g) the per-CU LDS unit
// is the shared bottleneck at high wave counts -- minimize wave-level LDS ops
// (b128 c-major reads instead of stride-3 b32).

// ---------------- K01: SJ/JT reductions + Rodrigues + B-frags + A-frags.
__global__ __launch_bounds__(256, 1) void k01_prep(
    const float* __restrict__ shapedirs,
    const float* __restrict__ posedirs,
    const float* __restrict__ Jreg,
    const float* __restrict__ vtemp,
    const float* __restrict__ theta,
    const float* __restrict__ beta,
    float* __restrict__ SJJT,     // ws, 528 floats
    float* __restrict__ RsOut,
    bf16x8* __restrict__ Bf,
    bf16x8* __restrict__ Af,
    int N)
{
    const int tid = threadIdx.x;
    const int rodBlocks = (N * NJ) / 256;        // 256
    const int nB = NTB * 5 * 64;                 // 49920
    const int bfBlocks = nB / 256;               // 195
    if (blockIdx.x < 44) {
        int task = blockIdx.x * 4 + (tid >> 6);   // 0..175
        int lane = tid & 63;
        if (task < 176) {
            int b = task >> 4;      // 0..10
            int j = task & 15;
            const float* src = (b < 10) ? (shapedirs + (size_t)b * M3) : vtemp;
            float a0 = 0.f, a1 = 0.f, a2 = 0.f;
            for (int v = lane; v < NV; v += 64) {
                float jr = Jreg[v * 16 + j];
                a0 = fmaf(src[v*3 + 0], jr, a0);
                a1 = fmaf(src[v*3 + 1], jr, a1);
                a2 = fmaf(src[v*3 + 2], jr, a2);
            }
#pragma unroll
            for (int m = 1; m < 64; m <<= 1) {
                a0 += __shfl_xor(a0, m);
                a1 += __shfl_xor(a1, m);
                a2 += __shfl_xor(a2, m);
            }
            if (lane == 0) {
                int base = (b < 10) ? (b*48 + j*3) : (480 + j*3);
                SJJT[base + 0] = a0;
                SJJT[base + 1] = a1;
                SJJT[base + 2] = a2;
            }
        }
        return;
    }
    if (blockIdx.x < 44 + rodBlocks) {
        int idx = (blockIdx.x - 44) * 256 + tid;
        int n = idx >> 4;
        int j = idx & 15;
        float r0,r1,r2,r3,r4,r5,r6,r7,r8;
        rodrigues9(theta[n*48 + j*3 + 0], theta[n*48 + j*3 + 1],
                   theta[n*48 + j*3 + 2], r0,r1,r2,r3,r4,r5,r6,r7,r8);
        float* R = RsOut + (size_t)idx * 9;
        R[0]=r0; R[1]=r1; R[2]=r2; R[3]=r3; R[4]=r4;
        R[5]=r5; R[6]=r6; R[7]=r7; R[8]=r8;
        return;
    }
    if (blockIdx.x < 44 + rodBlocks + bfBlocks) {
        int idx = (blockIdx.x - 44 - rodBlocks) * 256 + tid;
        int lane = idx & 63;
        int ks   = (idx >> 6) % 5;
        int nt   = idx / 320;
        int col = nt * 16 + (lane & 15);
        int k0  = ks * 32 + (lane >> 4) * 8;
        bf16x8 o;
#pragma unroll
        for (int j = 0; j < 8; ++j) {
            int k = k0 + j;
            float val = 0.f;
            if (col < M3) {
                if (k < 10)       val = shapedirs[(size_t)k * M3 + col];
                else if (k < 145) val = posedirs[(size_t)(k - 10) * M3 + col];
            }
            o[j] = (short)f2bf(val);
        }
        Bf[idx] = o;
        return;
    }
    // A-frag packing with INLINE Rodrigues (validated R23/R24)
    int idx = (blockIdx.x - 44 - rodBlocks - bfBlocks) * 256 + tid;
    int nA = (N / 16) * 5 * 64;
    if (idx >= nA) return;
    int lane = idx & 63;
    int ks   = (idx >> 6) % 5;
    int mt   = idx / 320;
    int n  = mt * 16 + (lane & 15);
    int k0 = ks * 32 + (lane >> 4) * 8;

    int kkA = k0 - 10;
    int jA  = (kkA < 0) ? 0 : (kkA > 134 ? 14 : kkA / 9);
    int kkB = k0 - 3;
    int jB  = (kkB < 0) ? 0 : (kkB > 134 ? 14 : kkB / 9);

    float ra0,ra1,ra2,ra3,ra4,ra5,ra6,ra7,ra8;
    rodrigues9(theta[n*48 + (jA+1)*3 + 0], theta[n*48 + (jA+1)*3 + 1],
               theta[n*48 + (jA+1)*3 + 2], ra0,ra1,ra2,ra3,ra4,ra5,ra6,ra7,ra8);
    float rb0,rb1,rb2,rb3,rb4,rb5,rb6,rb7,rb8;
    rodrigues9(theta[n*48 + (jB+1)*3 + 0], theta[n*48 + (jB+1)*3 + 1],
               theta[n*48 + (jB+1)*3 + 2], rb0,rb1,rb2,rb3,rb4,rb5,rb6,rb7,rb8);

    bf16x8 o;
#pragma unroll
    for (int j = 0; j < 8; ++j) {
        int k = k0 + j;
        float val;
        if (k < 10) {
            val = beta[(size_t)n * 10 + k];
        } else if (k < 145) {
            int kk = k - 10;
            int jj = kk / 9;
            int rr = kk - jj * 9;
            float sa = (rr==0)?ra0:(rr==1)?ra1:(rr==2)?ra2:(rr==3)?ra3:
                       (rr==4)?ra4:(rr==5)?ra5:(rr==6)?ra6:(rr==7)?ra7:ra8;
            float sb = (rr==0)?rb0:(rr==1)?rb1:(rr==2)?rb2:(rr==3)?rb3:
                       (rr==4)?rb4:(rr==5)?rb5:(rr==6)?rb6:(rr==7)?rb7:rb8;
            float vv = (jj == jA) ? sa : sb;
            if ((rr & 3) == 0) vv -= 1.f;
            val = vv;
        } else {
            val = 0.f;
        }
        o[j] = (short)f2bf(val);
    }
    Af[idx] = o;
}

// ---------------- K2C: kinematic chain -> Aws; zero joints for k34 atomics.
__global__ __launch_bounds__(256, 1) void k2c_chain(
    const float* __restrict__ beta,
    const float* __restrict__ Rs,
    const float* __restrict__ SJJT,   // ws
    float* __restrict__ Aws,
    float* __restrict__ joints,       // zeroed here
    int N)
{
    const int tid = threadIdx.x;
    const int KB = (N * 5 + 255) / 256;          // 80
    if (blockIdx.x >= KB) {
        int idx = (blockIdx.x - KB) * 256 + tid;
        if (idx < N * 48) joints[idx] = 0.f;
        return;
    }
    __shared__ float sS[528];
    for (int i = tid; i < 528; i += 256) sS[i] = SJJT[i];
    __syncthreads();
    int gid = blockIdx.x * 256 + tid;
    if (gid >= N * 5) return;
    int n  = gid / 5;
    int ch = gid % 5;

    float b[10];
#pragma unroll
    for (int i = 0; i < 10; ++i) b[i] = beta[n*10 + i];

    int jidx[4];
    jidx[0] = 0; jidx[1] = ch*3 + 1; jidx[2] = ch*3 + 2; jidx[3] = ch*3 + 3;
    float J[4][3];
#pragma unroll
    for (int q = 0; q < 4; ++q) {
        int j = jidx[q];
#pragma unroll
        for (int c = 0; c < 3; ++c) {
            float acc = sS[480 + j*3 + c];
#pragma unroll
            for (int qq = 0; qq < 10; ++qq)
                acc = fmaf(b[qq], sS[qq*48 + j*3 + c], acc);
            J[q][c] = acc;
        }
    }

    const float* Rn = Rs + (size_t)n * 144;
    float* An = Aws + (size_t)n * 192;

    float GpR[9], Gpt[3];
#pragma unroll
    for (int r = 0; r < 3; ++r) {
        GpR[r*3+0] =  Rn[r*3+0];
        GpR[r*3+1] = -Rn[r*3+1];
        GpR[r*3+2] = -Rn[r*3+2];
    }
    Gpt[0] = J[0][0]; Gpt[1] = J[0][1]; Gpt[2] = J[0][2];

    if (ch == 0) {
#pragma unroll
        for (int r = 0; r < 3; ++r) {
            float rel = GpR[r*3+0]*J[0][0] + GpR[r*3+1]*J[0][1] + GpR[r*3+2]*J[0][2];
            An[r*4 + 0] = GpR[r*3+0];
            An[r*4 + 1] = GpR[r*3+1];
            An[r*4 + 2] = GpR[r*3+2];
            An[r*4 + 3] = Gpt[r] - rel;
        }
    }

#pragma unroll
    for (int st = 0; st < 3; ++st) {
        int i = jidx[st+1];
        const float* Ri = Rn + (size_t)i * 9;
        float t0 = J[st+1][0] - J[st][0];
        float t1 = J[st+1][1] - J[st][1];
        float t2 = J[st+1][2] - J[st][2];
        float GR[9], Gt[3];
#pragma unroll
        for (int r = 0; r < 3; ++r) {
#pragma unroll
            for (int c = 0; c < 3; ++c)
                GR[r*3+c] = GpR[r*3+0]*Ri[c] + GpR[r*3+1]*Ri[3+c] + GpR[r*3+2]*Ri[6+c];
            Gt[r] = GpR[r*3+0]*t0 + GpR[r*3+1]*t1 + GpR[r*3+2]*t2 + Gpt[r];
        }
#pragma unroll
        for (int r = 0; r < 3; ++r) {
            float rel = GR[r*3+0]*J[st+1][0] + GR[r*3+1]*J[st+1][1] + GR[r*3+2]*J[st+1][2];
            An[i*12 + r*4 + 0] = GR[r*3+0];
            An[i*12 + r*4 + 1] = GR[r*3+1];
            An[i*12 + r*4 + 2] = GR[r*3+2];
            An[i*12 + r*4 + 3] = Gt[r] - rel;
        }
#pragma unroll
        for (int r = 0; r < 9; ++r) GpR[r] = GR[r];
        Gpt[0] = Gt[0]; Gpt[1] = Gt[1]; Gpt[2] = Gt[2];
    }
}

// ---------------- K34: MFMA GEMM + LBS blend + partial joints (atomics).
// LDS reused: phases 1-2 as [16][194] (SCg); phase 3 as c-major [3][16][68]
// (SCj: 16B-aligned rows, s-groups on banks 0/4/8/12 -> conflict-free b128).
__global__ __launch_bounds__(256, 1) void k34_gemm_blend(
    const bf16x8* __restrict__ Af,      // [(N/16)][5][64]
    const bf16x8* __restrict__ Bf,      // [NTB][5][64]
    const float* __restrict__ vtemp,
    const float* __restrict__ Aws,
    const float* __restrict__ weights,
    const float* __restrict__ Jreg,
    float* __restrict__ verts,
    float* __restrict__ joints,         // accumulated via atomicAdd
    int N)
{
    __shared__ __attribute__((aligned(16))) float sC[3264];  // max(16*194, 3*16*68)
#define SCg(r_, c_) sC[(r_) * 194 + (c_)]
#define SCj(c_, s_, v_) sC[(c_) * 1088 + (s_) * 68 + (v_)]
    const int tid  = threadIdx.x;
    const int w    = tid >> 6;
    const int lane = tid & 63;
    const int mt   = blockIdx.x;                 // 16 samples
    const int ntb  = blockIdx.y * 12 + w * 3;    // B n-tile base for this wave

    f32x4 acc0 = {0.f,0.f,0.f,0.f};
    f32x4 acc1 = {0.f,0.f,0.f,0.f};
    f32x4 acc2 = {0.f,0.f,0.f,0.f};

    const bf16x8* Ab = Af + (size_t)mt * 5 * 64 + lane;
    const bf16x8* Bb = Bf + lane;

#pragma unroll
    for (int ks = 0; ks < 5; ++ks) {
        bf16x8 a  = Ab[ks * 64];
        bf16x8 b0 = Bb[((size_t)(ntb+0) * 5 + ks) * 64];
        bf16x8 b1 = Bb[((size_t)(ntb+1) * 5 + ks) * 64];
        bf16x8 b2 = Bb[((size_t)(ntb+2) * 5 + ks) * 64];
        acc0 = __builtin_amdgcn_mfma_f32_16x16x32_bf16(a, b0, acc0, 0, 0, 0);
        acc1 = __builtin_amdgcn_mfma_f32_16x16x32_bf16(a, b1, acc1, 0, 0, 0);
        acc2 = __builtin_amdgcn_mfma_f32_16x16x32_bf16(a, b2, acc2, 0, 0, 0);
    }

    // C/D layout: col = lane&15, row = (lane>>4)*4 + r  [m89-verified]
    {
        const int rl = (lane >> 4) * 4;
        const int cl = w * 48 + (lane & 15);
#pragma unroll
        for (int r = 0; r < 4; ++r) {
            SCg(rl + r, cl +  0) = acc0[r];
            SCg(rl + r, cl + 16) = acc1[r];
            SCg(rl + r, cl + 32) = acc2[r];
        }
    }
    __syncthreads();

    // ---- blend phase (read SCg, hold results in regs; scalar-A path)
    const int vg = blockIdx.y * 64 + lane;
    const bool valid = vg < NV;
    const int cvg = valid ? vg : (NV - 1);

    const float4* wrow = reinterpret_cast<const float4*>(&weights[(size_t)cvg * 16]);
    float vtx = vtemp[cvg*3 + 0];
    float vty = vtemp[cvg*3 + 1];
    float vtz = vtemp[cvg*3 + 2];

    float res[12];
#pragma unroll
    for (int it = 0; it < 4; ++it) {
        const int nl = w * 4 + it;
        const int n  = __builtin_amdgcn_readfirstlane(mt * 16 + nl);
        const float* An = Aws + (size_t)n * 192;     // uniform -> s_load path

        float px = SCg(nl, lane*3 + 0) + vtx;
        float py = SCg(nl, lane*3 + 1) + vty;
        float pz = SCg(nl, lane*3 + 2) + vtz;

        float ox = 0.f, oy = 0.f, oz = 0.f;
#pragma unroll
        for (int q = 0; q < 4; ++q) {
            float4 wq = wrow[q];
#define BJQ(jj_, ww_) { \
            const float* ap = An + (4*q + jj_) * 12; \
            float a0=ap[0], a1=ap[1], a2 =ap[2],  a3 =ap[3]; \
            float a4=ap[4], a5=ap[5], a6 =ap[6],  a7 =ap[7]; \
            float a8=ap[8], a9=ap[9], a10=ap[10], a11=ap[11]; \
            float X = fmaf(a0,px, fmaf(a1,py, fmaf(a2,pz, a3))); \
            float Y = fmaf(a4,px, fmaf(a5,py, fmaf(a6,pz, a7))); \
            float Z = fmaf(a8,px, fmaf(a9,py, fmaf(a10,pz, a11))); \
            ox = fmaf(ww_, X, ox); oy = fmaf(ww_, Y, oy); oz = fmaf(ww_, Z, oz); }
            BJQ(0, wq.x) BJQ(1, wq.y) BJQ(2, wq.z) BJQ(3, wq.w)
#undef BJQ
        }
        res[it*3+0] = ox; res[it*3+1] = oy; res[it*3+2] = oz;
    }
    __syncthreads();   // all blend reads of SCg complete

    // write blended verts to global and into c-major LDS (zeros for invalid)
#pragma unroll
    for (int it = 0; it < 4; ++it) {
        const int nl = w * 4 + it;
        SCj(0, nl, lane) = valid ? res[it*3+0] : 0.f;
        SCj(1, nl, lane) = valid ? res[it*3+1] : 0.f;
        SCj(2, nl, lane) = valid ? res[it*3+2] : 0.f;
        if (valid) {
            float* o = verts + (size_t)(mt*16 + nl) * M3 + (size_t)vg * 3;
            o[0] = res[it*3+0]; o[1] = res[it*3+1]; o[2] = res[it*3+2];
        }
    }
    __syncthreads();

    // ---- partial joints: task (s = tid>>4, j = tid&15); b128 c-major reads
    {
        const int s  = tid >> 4;
        const int j  = tid & 15;
        const int vb = blockIdx.y * 64;
        const float4* xr = reinterpret_cast<const float4*>(&SCj(0, s, 0));
        const float4* yr = reinterpret_cast<const float4*>(&SCj(1, s, 0));
        const float4* zr = reinterpret_cast<const float4*>(&SCj(2, s, 0));
        float a0 = 0.f, a1 = 0.f, a2 = 0.f;
#pragma unroll 4
        for (int v4 = 0; v4 < 16; ++v4) {
            int v0 = vb + v4*4;
            float jr0 = (v0+0 < NV) ? Jreg[(size_t)(v0+0) * 16 + j] : 0.f;
            float jr1 = (v0+1 < NV) ? Jreg[(size_t)(v0+1) * 16 + j] : 0.f;
            float jr2 = (v0+2 < NV) ? Jreg[(size_t)(v0+2) * 16 + j] : 0.f;
            float jr3 = (v0+3 < NV) ? Jreg[(size_t)(v0+3) * 16 + j] : 0.f;
            float4 x4 = xr[v4], y4 = yr[v4], z4 = zr[v4];
            a0 = fmaf(jr0, x4.x, fmaf(jr1, x4.y, fmaf(jr2, x4.z, fmaf(jr3, x4.w, a0))));
            a1 = fmaf(jr0, y4.x, fmaf(jr1, y4.y, fmaf(jr2, y4.z, fmaf(jr3, y4.w, a1))));
            a2 = fmaf(jr0, z4.x, fmaf(jr1, z4.y, fmaf(jr2, z4.z, fmaf(jr3, z4.w, a2))));
        }
        float* jp = joints + (size_t)(mt * 16 + s) * 48 + j * 3;
        atomicAdd(&jp[0], a0);
        atomicAdd(&jp[1], a1);
        atomicAdd(&jp[2], a2);
    }
#undef SCg
#undef SCj
}

extern "C" void kernel_launch(void* const* d_in, const int* in_sizes, int n_in,
                              void* d_out, int out_size, void* d_ws, size_t ws_size,
                              hipStream_t stream)
{
    const float* beta   = (const float*)d_in[0];
    const float* theta  = (const float*)d_in[1];
    const float* vtemp  = (const float*)d_in[2];
    const float* shaped = (const float*)d_in[3];
    const float* Jreg   = (const float*)d_in[4];
    const float* posed  = (const float*)d_in[5];
    const float* wts    = (const float*)d_in[6];
    float* out = (float*)d_out;
    const int N = in_sizes[0] / 10;   // 4096

    float* verts  = out;                            // N*2334
    float* joints = out + (size_t)N * M3;           // N*48
    float* RsOut  = joints + (size_t)N * 48;        // N*144
    float* Aws    = (float*)d_ws;                   // N*192
    float*  fbase = Aws + (size_t)N * 192;
    const int nA = (N / 16) * 5 * 64;
    const int nB = NTB * 5 * 64;
    bf16x8* Af    = (bf16x8*)fbase;                      // nA * 16B
    bf16x8* Bf    = (bf16x8*)(fbase + (size_t)nA * 4);   // nB * 16B
    float*  sjjt  = fbase + (size_t)nA * 4 + (size_t)nB * 4;  // 528 floats

    const int rodBlocks = (N * NJ) / 256;
    const int zeroBlocks = (N * 48 + 255) / 256;

    k01_prep<<<44 + rodBlocks + nB/256 + nA/256, 256, 0, stream>>>(
        shaped, posed, Jreg, vtemp, theta, beta, sjjt, RsOut, Bf, Af, N);
    k2c_chain<<<(N*5 + 255)/256 + zeroBlocks, 256, 0, stream>>>(
        beta, RsOut, sjjt, Aws, joints, N);
    k34_gemm_blend<<<dim3(N/16, 13), 256, 0, stream>>>(
        Af, Bf, vtemp, Aws, wts, Jreg, verts, joints, N);
}